// Round 10
// baseline (7616.226 us; speedup 1.0000x reference)
//
#include <hip/hip_runtime.h>
#include <hip/hip_bf16.h>

#define NC 4096
#define NSTEP 2500

typedef float v4f __attribute__((ext_vector_type(4)));
typedef short v8s __attribute__((ext_vector_type(8)));
typedef unsigned int v4u __attribute__((ext_vector_type(4)));
typedef unsigned long long u64;

// ws layout (bytes):
//   [0,1024)        (unused -- was tags)
//   [1024,1088)     accum[16] (float)     -- readout partial sums
//   [4096,69632)    ring[2][4][4096] bf16 -- double-buffered r broadcast
//
// Self-validating transport: bit0 of every aligned ring u64 (4 bf16 values)
// is a step-parity stamp p(m) = (m>>1)&1 of the r_m it carries. 8B publishes
// are single-copy atomic, so a reader granule is valid iff its u64 parities
// match the expected p(t). Drift is bounded <2 steps by the global
// dependency, so the only same-slot confusion candidate is r_t vs r_{t+-2},
// which parity distinguishes.
//
// Round-10 = isolation: r7's measured-best protocol (simple 2-instruction
// probe spin, wave0 spec-fetch, atomic-swap publish, publish-early) + r9's
// two wait-removal components (raw lgkmcnt-only barrier, pipelined noise),
// WITHOUT r9's masked probe (isolated regression: VALUBusy 7->9.2, +200us
// -- extra VALU in the innermost spin slows sampling for all 2048 waves).
#define WS_WORDS 17408  // zero first 69632 bytes (+ slot1 parity-invalid init)

__device__ __forceinline__ short f2bf_s(float f) {
  __hip_bfloat16 h = __float2bfloat16(f);
  return __bfloat16_as_short(h);
}

__device__ __forceinline__ unsigned pack_bf2(float a, float b) {
  unsigned ua = (unsigned short)f2bf_s(a);
  unsigned ub = (unsigned short)f2bf_s(b);
  return ua | (ub << 16);
}

// barrier WITHOUT the compiler's vmcnt(0) drain: LDS ordering only.
// Cross-wave data (red, rbuf) moves exclusively through LDS; each wave
// drains its own DS ops via lgkmcnt(0) before s_barrier.
__device__ __forceinline__ void barrier_lds_only() {
  asm volatile("s_waitcnt lgkmcnt(0)\n\ts_barrier" ::: "memory");
}

__global__ void rnn_init(unsigned* ws_u) {
  int i = blockIdx.x * blockDim.x + threadIdx.x;
  if (i >= WS_WORDS) return;
  // slot0 (words [1024,9216)) = 0: r_0 = 0, parity bit0 = 0 = valid for t=0.
  // slot1 (words [9216,17408)): u64 = 0x...0001 -> parity 1 = "r_1 not here".
  unsigned v = 0u;
  if (i >= 9216 && (i & 1) == 0) v = 1u;
  ws_u[i] = v;
}

__global__ __launch_bounds__(512, 2) void rnn_persist(
    const float* __restrict__ x, const float* __restrict__ rec_w,
    const float* __restrict__ rec_b, const float* __restrict__ inp_w,
    const float* __restrict__ out_w, const float* __restrict__ mem_w,
    const float* __restrict__ noise, float* __restrict__ ws) {
  const int cu   = blockIdx.x;       // 0..255, owns rows [cu*16, cu*16+16)
  const int tid  = threadIdx.x;
  const int wave = tid >> 6;         // 0..7, K-slice [wave*512, +512)
  const int lane = tid & 63;
  const int n    = lane & 15;        // MFMA col (batch; valid < 4) / A row
  const int g    = lane >> 4;        // quad
  const int row0 = cu << 4;

  float* accum         = ws + 256;
  __hip_bfloat16* ring = (__hip_bfloat16*)(ws + 1024);

  // full r_t staged, swizzled: batch stride 1032 u64 = 8256 B (== 64 mod 128
  // -> B-frag ds_read_b128 worst case 2-way aliasing = free per m136)
  __shared__ u64 rbuf64[4 * 1032];       // 33 KB
  __shared__ v4f red[2][8][64];          // 16 KB, double-buffered by t&1
  const unsigned short* rbufs = (const unsigned short*)rbuf64;

  // collapsing anti-hang valve: never fires when the protocol is live;
  // after a first fire the budget drops so a genuine failure exits fast
  // (passed:false) instead of masquerading as a container timeout.
  int vlimit = 1 << 19;

  // ---- W A-fragments in VGPRs: lane holds W[row0+n][k = wave*512+f*32+g*8+j]
  v8s wfrag[16];
  {
    const float* wp = rec_w + (size_t)(row0 + n) * NC + wave * 512 + g * 8;
#pragma unroll
    for (int f = 0; f < 16; ++f) {
      const float* p = wp + f * 32;
      float4 a = *(const float4*)p;
      float4 b = *(const float4*)(p + 4);
      v8s w;
      w[0] = f2bf_s(a.x); w[1] = f2bf_s(a.y); w[2] = f2bf_s(a.z); w[3] = f2bf_s(a.w);
      w[4] = f2bf_s(b.x); w[5] = f2bf_s(b.y); w[6] = f2bf_s(b.z); w[7] = f2bf_s(b.w);
      wfrag[f] = w;
    }
  }

  // ---- wave0 per-lane state: rows row0+4g+q, batch b=n&3
  float rst[4] = {0, 0, 0, 0}, tmem[4] = {0, 0, 0, 0}, tout[4] = {0, 0, 0, 0};
  float bias[4] = {0, 0, 0, 0}, esmp[4] = {0, 0, 0, 0}, etst[4] = {0, 0, 0, 0};
  float4 nz_cur = {0.f, 0.f, 0.f, 0.f};
  if (wave == 0) {
    float4 bb = *(const float4*)(rec_b + row0 + g * 4);
    bias[0] = bb.x; bias[1] = bb.y; bias[2] = bb.z; bias[3] = bb.w;
    const int b = n & 3;
    float xs0 = x[b * 4 + 0], xs1 = x[b * 4 + 1];
    float xt0 = x[b * 4 + 2], xt1 = x[b * 4 + 3];
#pragma unroll
    for (int q = 0; q < 4; ++q) {
      int i = row0 + g * 4 + q;
      float w0 = inp_w[2 * i], w1 = inp_w[2 * i + 1];
      esmp[q] = xs0 * w0 + xs1 * w1;
      etst[q] = xt0 * w0 + xt1 * w1;
    }
    nz_cur = *(const float4*)(noise + row0 + g * 4);  // row 0 prologue
  }

  for (int t = 0; t < NSTEP; ++t) {
    const int slot = t & 1;
    const unsigned par = (unsigned)((t >> 1) & 1);

    // ---- merged poll+stage, per-wave autonomous: wave w consumes exactly
    // publishers [32w, 32w+32), covered by its own lanes' granules. No
    // pre-barrier; each wave proceeds as soon as ITS slice of r_t arrives.
    {
      const v4u* src = (const v4u*)((const u64*)ring + (size_t)slot * 4096);
      const v4u* a0 = src + tid;
      const v4u* a1 = src + tid + 512;
      const v4u* a2 = src + tid + 1024;
      const v4u* a3 = src + tid + 1536;
      v4u d0, d1, d2, d3;
      bool need = true;

      if (wave == 0) {
        // speculative full fetch: its vmcnt(0) retires the outstanding
        // publish swap + noise prefetch IN PARALLEL with the fetch RT, and
        // wave0 starts late enough (tail work) that its publishers 0..31
        // often already landed.
        asm volatile(
            "global_load_dwordx4 %0, %4, off sc1\n\t"
            "global_load_dwordx4 %1, %5, off sc1\n\t"
            "global_load_dwordx4 %2, %6, off sc1\n\t"
            "global_load_dwordx4 %3, %7, off sc1\n\t"
            "s_waitcnt vmcnt(0)"
            : "=v"(d0), "=v"(d1), "=v"(d2), "=v"(d3)
            : "v"(a0), "v"(a1), "v"(a2), "v"(a3)
            : "memory");
        unsigned bad = (d0.x ^ par) | (d0.z ^ par) | (d1.x ^ par) |
                       (d1.z ^ par) | (d2.x ^ par) | (d2.z ^ par) |
                       (d3.x ^ par) | (d3.z ^ par);
        need = !__all((bad & 1u) == 0u);
      }

      if (need) {
        // minimal 2-instruction probe spin (r2/r7 protocol, measured best;
        // masked/dual variants add spin VALU -> slower sampling -> regress)
        int guard = 0;
        while (true) {
          u64 pr;
          asm volatile(
              "global_load_dwordx2 %0, %1, off sc1\n\t"
              "s_waitcnt vmcnt(0)"
              : "=v"(pr) : "v"((const u64*)a0) : "memory");
          if (__all((((unsigned)pr ^ par) & 1u) == 0u)) break;
          if (++guard > vlimit) { vlimit = 256; break; }  // anti-hang valve
        }

        // full fetch + verify (sibling sectors may stagger; usually 1 pass)
        guard = 0;
        while (true) {
          asm volatile(
              "global_load_dwordx4 %0, %4, off sc1\n\t"
              "global_load_dwordx4 %1, %5, off sc1\n\t"
              "global_load_dwordx4 %2, %6, off sc1\n\t"
              "global_load_dwordx4 %3, %7, off sc1\n\t"
              "s_waitcnt vmcnt(0)"
              : "=v"(d0), "=v"(d1), "=v"(d2), "=v"(d3)
              : "v"(a0), "v"(a1), "v"(a2), "v"(a3)
              : "memory");
          unsigned bad = (d0.x ^ par) | (d0.z ^ par) | (d1.x ^ par) |
                         (d1.z ^ par) | (d2.x ^ par) | (d2.z ^ par) |
                         (d3.x ^ par) | (d3.z ^ par);
          if (__all((bad & 1u) == 0u)) break;
          if (++guard > vlimit) { vlimit = 256; break; }  // anti-hang valve
        }
      }

      // stage to wave-private LDS region (DS ops in-order within a wave;
      // this wave's MFMA reads exactly the region it writes -> no barrier)
      *(v4u*)(rbuf64 + 0 * 1032 + tid * 2) = d0;
      *(v4u*)(rbuf64 + 1 * 1032 + tid * 2) = d1;
      *(v4u*)(rbuf64 + 2 * 1032 + tid * 2) = d2;
      *(v4u*)(rbuf64 + 3 * 1032 + tid * 2) = d3;
    }

    // ---- noise prefetch for step t+1: issued AFTER discovery (its HBM
    // latency is NOT inside this step's vmcnt(0) drains) and BEFORE the
    // MFMA/barrier -- the raw barrier below does not drain vmcnt, so it
    // retires across barrier + tail, off the gating path.
    float4 nz_next = {0.f, 0.f, 0.f, 0.f};
    if (wave == 0) {
      int tn = (t < NSTEP - 1) ? t + 1 : t;
      nz_next = *(const float4*)(noise + (size_t)tn * NC + row0 + g * 4);
    }

    // ---- B-frags: lane holds r[b=n&3][k = wave*512+f*32+g*8+j]
    // 4 independent accumulator chains: dependent-latency -> issue-limited
    const unsigned short* rb = rbufs + (n & 3) * 4128 + wave * 512 + g * 8;
    v4f ac0 = {0.f, 0.f, 0.f, 0.f}, ac1 = {0.f, 0.f, 0.f, 0.f};
    v4f ac2 = {0.f, 0.f, 0.f, 0.f}, ac3 = {0.f, 0.f, 0.f, 0.f};
#pragma unroll
    for (int f = 0; f < 16; f += 4) {
      v8s b0 = *(const v8s*)(rb + (f + 0) * 32);
      v8s b1 = *(const v8s*)(rb + (f + 1) * 32);
      v8s b2 = *(const v8s*)(rb + (f + 2) * 32);
      v8s b3 = *(const v8s*)(rb + (f + 3) * 32);
      ac0 = __builtin_amdgcn_mfma_f32_16x16x32_bf16(wfrag[f + 0], b0, ac0, 0, 0, 0);
      ac1 = __builtin_amdgcn_mfma_f32_16x16x32_bf16(wfrag[f + 1], b1, ac1, 0, 0, 0);
      ac2 = __builtin_amdgcn_mfma_f32_16x16x32_bf16(wfrag[f + 2], b2, ac2, 0, 0, 0);
      ac3 = __builtin_amdgcn_mfma_f32_16x16x32_bf16(wfrag[f + 3], b3, ac3, 0, 0, 0);
    }
    red[slot][wave][lane] = (ac0 + ac1) + (ac2 + ac3);
    barrier_lds_only();  // reduction barrier; vmem stays in flight

    if (wave == 0) {
      // pairwise tree: 3-deep dependent chain instead of 7-deep
      v4f s01 = red[slot][0][lane] + red[slot][1][lane];
      v4f s23 = red[slot][2][lane] + red[slot][3][lane];
      v4f s45 = red[slot][4][lane] + red[slot][5][lane];
      v4f s67 = red[slot][6][lane] + red[slot][7][lane];
      v4f s = (s01 + s23) + (s45 + s67);
      const int ph = t / 500;  // 0 fix, 1 sample, 2 delay, 3 test, 4 response
#pragma unroll
      for (int q = 0; q < 4; ++q) {
        float e = (ph == 1) ? esmp[q] : ((ph == 3) ? etst[q] : 0.f);
        float pre = s[q] + bias[q] + e;
        float rl = pre > 0.f ? pre : 0.f;
        float nq = (q == 0) ? nz_cur.x : (q == 1) ? nz_cur.y
                 : (q == 2) ? nz_cur.z : nz_cur.w;
        rst[q] = 0.8f * rst[q] + 0.2f * rl + 0.02f * nq;
      }
      if (n < 4) {  // publish FIRST (before bookkeeping): every cycle earlier
                    // here is a cycle off every consumer's discovery chain.
        u64 v = (u64)pack_bf2(rst[0], rst[1]) |
                ((u64)pack_bf2(rst[2], rst[3]) << 32);
        v = (v & ~1ull) | (u64)(((t + 1) >> 1) & 1u);
        u64* dst =
            (u64*)(ring + ((size_t)((t + 1) & 1) * 4 + n) * NC + row0 + g * 4);
        asm volatile("global_atomic_swap_x2 %0, %1, off sc1"
                     :: "v"(dst), "v"(v) : "memory");
      }
      if (t >= 1000 && t < 1500) {
#pragma unroll
        for (int q = 0; q < 4; ++q) tmem[q] += rst[q];
      }
      if (t >= 2000) {
#pragma unroll
        for (int q = 0; q < 4; ++q) tout[q] += rst[q];
      }
      nz_cur = nz_next;  // pipelined noise: consumed next step
      // no ack, no tag: validity travels inside the data
    }
  }

  // ---- readout partials: out[s][b][o] += sum_i w[o][i] * tsum[b][i]
  if (wave == 0) {
    float pm0 = 0, pm1 = 0, po0 = 0, po1 = 0;
#pragma unroll
    for (int q = 0; q < 4; ++q) {
      int i = row0 + g * 4 + q;
      pm0 += mem_w[i] * tmem[q];
      pm1 += mem_w[NC + i] * tmem[q];
      po0 += out_w[i] * tout[q];
      po1 += out_w[NC + i] * tout[q];
    }
    pm0 += __shfl_xor(pm0, 16); pm0 += __shfl_xor(pm0, 32);
    pm1 += __shfl_xor(pm1, 16); pm1 += __shfl_xor(pm1, 32);
    po0 += __shfl_xor(po0, 16); po0 += __shfl_xor(po0, 32);
    po1 += __shfl_xor(po1, 16); po1 += __shfl_xor(po1, 32);
    if (lane < 4) {
      atomicAdd(&accum[lane * 2 + 0], pm0);
      atomicAdd(&accum[lane * 2 + 1], pm1);
      atomicAdd(&accum[8 + lane * 2 + 0], po0);
      atomicAdd(&accum[8 + lane * 2 + 1], po1);
    }
  }
}

// Output is FLOAT32 (reference returns f32)
__global__ void rnn_final(const float* __restrict__ ws, float* __restrict__ out) {
  int i = threadIdx.x;
  if (i < 16) out[i] = ws[256 + i] * (1.0f / 500.0f);
}

extern "C" void kernel_launch(void* const* d_in, const int* in_sizes, int n_in,
                              void* d_out, int out_size, void* d_ws, size_t ws_size,
                              hipStream_t stream) {
  (void)in_sizes; (void)n_in; (void)out_size; (void)ws_size;
  const float* x     = (const float*)d_in[0];
  const float* rec_w = (const float*)d_in[1];
  const float* rec_b = (const float*)d_in[2];
  const float* inp_w = (const float*)d_in[3];
  const float* out_w = (const float*)d_in[4];
  const float* mem_w = (const float*)d_in[5];
  const float* noise = (const float*)d_in[6];
  float* ws = (float*)d_ws;

  rnn_init<<<(WS_WORDS + 255) / 256, 256, 0, stream>>>((unsigned*)d_ws);
  rnn_persist<<<256, 512, 0, stream>>>(x, rec_w, rec_b, inp_w, out_w, mem_w,
                                       noise, ws);
  rnn_final<<<1, 64, 0, stream>>>(ws, (float*)d_out);
}

// Round 11
// 5646.670 us; speedup vs baseline: 1.3488x; 1.3488x over previous
//
#include <hip/hip_runtime.h>
#include <hip/hip_bf16.h>

#define NC 4096
#define NSTEP 2500

typedef float v4f __attribute__((ext_vector_type(4)));
typedef short v8s __attribute__((ext_vector_type(8)));
typedef unsigned int v4u __attribute__((ext_vector_type(4)));
typedef unsigned long long u64;

// ws layout (bytes):
//   [0,1024)        (unused -- was tags)
//   [1024,1088)     accum[16] (float)     -- readout partial sums
//   [4096,69632)    ring[2][4][4096] bf16 -- double-buffered r broadcast
//
// Self-validating transport: bit0 of every aligned ring u64 (4 bf16 values)
// is a step-parity stamp p(m) = (m>>1)&1 of the r_m it carries. 8B publishes
// are single-copy atomic, so a reader granule is valid iff its u64 parities
// match the expected p(t). Drift is bounded <2 steps by the global
// dependency, so the only same-slot confusion candidate is r_t vs r_{t+-2},
// which parity distinguishes.
//
// Round-11 = EXACT r7 base (measured best, 7230us; r9/r10's barrier/noise
// changes both regressed and are reverted) + ONE change: s_sleep 12 (~768cy,
// SALU-only) at probe-spin entry. Congestion theory: 2048 waves x 16 MALL
// lines/probe at ~600cy period ~= 8+ TB/s of probe reads -- the spin itself
// congests the fabric that publish commits and fetches traverse (explains
// r3/r4/r9: more traffic AND slower sampling both lose). Entry-sleep cuts
// ~1/3 of probe iterations (the early, useless ones) with zero spin-loop
// instruction cost; hidden under the wait for exactly the gating waves.
#define WS_WORDS 17408  // zero first 69632 bytes (+ slot1 parity-invalid init)

__device__ __forceinline__ short f2bf_s(float f) {
  __hip_bfloat16 h = __float2bfloat16(f);
  return __bfloat16_as_short(h);
}

__device__ __forceinline__ unsigned pack_bf2(float a, float b) {
  unsigned ua = (unsigned short)f2bf_s(a);
  unsigned ub = (unsigned short)f2bf_s(b);
  return ua | (ub << 16);
}

__global__ void rnn_init(unsigned* ws_u) {
  int i = blockIdx.x * blockDim.x + threadIdx.x;
  if (i >= WS_WORDS) return;
  // slot0 (words [1024,9216)) = 0: r_0 = 0, parity bit0 = 0 = valid for t=0.
  // slot1 (words [9216,17408)): u64 = 0x...0001 -> parity 1 = "r_1 not here".
  unsigned v = 0u;
  if (i >= 9216 && (i & 1) == 0) v = 1u;
  ws_u[i] = v;
}

__global__ __launch_bounds__(512, 2) void rnn_persist(
    const float* __restrict__ x, const float* __restrict__ rec_w,
    const float* __restrict__ rec_b, const float* __restrict__ inp_w,
    const float* __restrict__ out_w, const float* __restrict__ mem_w,
    const float* __restrict__ noise, float* __restrict__ ws) {
  const int cu   = blockIdx.x;       // 0..255, owns rows [cu*16, cu*16+16)
  const int tid  = threadIdx.x;
  const int wave = tid >> 6;         // 0..7, K-slice [wave*512, +512)
  const int lane = tid & 63;
  const int n    = lane & 15;        // MFMA col (batch; valid < 4) / A row
  const int g    = lane >> 4;        // quad
  const int row0 = cu << 4;

  float* accum         = ws + 256;
  __hip_bfloat16* ring = (__hip_bfloat16*)(ws + 1024);

  // full r_t staged, swizzled: batch stride 1032 u64 = 8256 B (== 64 mod 128
  // -> B-frag ds_read_b128 worst case 2-way aliasing = free per m136)
  __shared__ u64 rbuf64[4 * 1032];       // 33 KB
  __shared__ v4f red[2][8][64];          // 16 KB, double-buffered by t&1
  const unsigned short* rbufs = (const unsigned short*)rbuf64;

  // collapsing anti-hang valve: never fires when the protocol is live;
  // after a first fire the budget drops so a genuine failure exits fast
  // (passed:false) instead of masquerading as a container timeout.
  int vlimit = 1 << 19;

  // ---- W A-fragments in VGPRs: lane holds W[row0+n][k = wave*512+f*32+g*8+j]
  v8s wfrag[16];
  {
    const float* wp = rec_w + (size_t)(row0 + n) * NC + wave * 512 + g * 8;
#pragma unroll
    for (int f = 0; f < 16; ++f) {
      const float* p = wp + f * 32;
      float4 a = *(const float4*)p;
      float4 b = *(const float4*)(p + 4);
      v8s w;
      w[0] = f2bf_s(a.x); w[1] = f2bf_s(a.y); w[2] = f2bf_s(a.z); w[3] = f2bf_s(a.w);
      w[4] = f2bf_s(b.x); w[5] = f2bf_s(b.y); w[6] = f2bf_s(b.z); w[7] = f2bf_s(b.w);
      wfrag[f] = w;
    }
  }

  // ---- wave0 per-lane state: rows row0+4g+q, batch b=n&3
  float rst[4] = {0, 0, 0, 0}, tmem[4] = {0, 0, 0, 0}, tout[4] = {0, 0, 0, 0};
  float bias[4] = {0, 0, 0, 0}, esmp[4] = {0, 0, 0, 0}, etst[4] = {0, 0, 0, 0};
  if (wave == 0) {
    float4 bb = *(const float4*)(rec_b + row0 + g * 4);
    bias[0] = bb.x; bias[1] = bb.y; bias[2] = bb.z; bias[3] = bb.w;
    const int b = n & 3;
    float xs0 = x[b * 4 + 0], xs1 = x[b * 4 + 1];
    float xt0 = x[b * 4 + 2], xt1 = x[b * 4 + 3];
#pragma unroll
    for (int q = 0; q < 4; ++q) {
      int i = row0 + g * 4 + q;
      float w0 = inp_w[2 * i], w1 = inp_w[2 * i + 1];
      esmp[q] = xs0 * w0 + xs1 * w1;
      etst[q] = xt0 * w0 + xt1 * w1;
    }
  }

  for (int t = 0; t < NSTEP; ++t) {
    const int slot = t & 1;
    const unsigned par = (unsigned)((t >> 1) & 1);
    float4 nz = {0.f, 0.f, 0.f, 0.f};
    if (wave == 0) {
      // prefetch noise; its latency hides under the fetch/poll phase
      nz = *(const float4*)(noise + (size_t)t * NC + row0 + g * 4);
    }

    // ---- merged poll+stage, per-wave autonomous: wave w consumes exactly
    // publishers [32w, 32w+32), covered by its own lanes' granules. No
    // pre-barrier; each wave proceeds as soon as ITS slice of r_t arrives.
    {
      const v4u* src = (const v4u*)((const u64*)ring + (size_t)slot * 4096);
      const v4u* a0 = src + tid;
      const v4u* a1 = src + tid + 512;
      const v4u* a2 = src + tid + 1024;
      const v4u* a3 = src + tid + 1536;
      v4u d0, d1, d2, d3;
      bool need = true;

      if (wave == 0) {
        // speculative full fetch: its vmcnt(0) retires the outstanding
        // publish swap + noise prefetch IN PARALLEL with the fetch RT, and
        // wave0 starts late enough (tail work) that its publishers 0..31
        // often already landed.
        asm volatile(
            "global_load_dwordx4 %0, %4, off sc1\n\t"
            "global_load_dwordx4 %1, %5, off sc1\n\t"
            "global_load_dwordx4 %2, %6, off sc1\n\t"
            "global_load_dwordx4 %3, %7, off sc1\n\t"
            "s_waitcnt vmcnt(0)"
            : "=v"(d0), "=v"(d1), "=v"(d2), "=v"(d3)
            : "v"(a0), "v"(a1), "v"(a2), "v"(a3)
            : "memory");
        unsigned bad = (d0.x ^ par) | (d0.z ^ par) | (d1.x ^ par) |
                       (d1.z ^ par) | (d2.x ^ par) | (d2.z ^ par) |
                       (d3.x ^ par) | (d3.z ^ par);
        need = !__all((bad & 1u) == 0u);
      }

      if (need) {
        // entry backoff: a wave reaching here is EARLY (its data hasn't
        // landed). ~768cy SALU sleep skips the useless early probes --
        // chip-wide probe traffic drops ~1/3 with zero spin-loop cost.
        // Hidden under the wait for the gating (longest-waiting) waves.
        asm volatile("s_sleep 12" :::);
        // minimal 2-instruction probe spin (r2/r7 protocol, measured best;
        // masked/dual variants add spin VALU -> slower sampling -> regress)
        int guard = 0;
        while (true) {
          u64 pr;
          asm volatile(
              "global_load_dwordx2 %0, %1, off sc1\n\t"
              "s_waitcnt vmcnt(0)"
              : "=v"(pr) : "v"((const u64*)a0) : "memory");
          if (__all((((unsigned)pr ^ par) & 1u) == 0u)) break;
          if (++guard > vlimit) { vlimit = 256; break; }  // anti-hang valve
        }

        // full fetch + verify (sibling sectors may stagger; usually 1 pass)
        guard = 0;
        while (true) {
          asm volatile(
              "global_load_dwordx4 %0, %4, off sc1\n\t"
              "global_load_dwordx4 %1, %5, off sc1\n\t"
              "global_load_dwordx4 %2, %6, off sc1\n\t"
              "global_load_dwordx4 %3, %7, off sc1\n\t"
              "s_waitcnt vmcnt(0)"
              : "=v"(d0), "=v"(d1), "=v"(d2), "=v"(d3)
              : "v"(a0), "v"(a1), "v"(a2), "v"(a3)
              : "memory");
          unsigned bad = (d0.x ^ par) | (d0.z ^ par) | (d1.x ^ par) |
                         (d1.z ^ par) | (d2.x ^ par) | (d2.z ^ par) |
                         (d3.x ^ par) | (d3.z ^ par);
          if (__all((bad & 1u) == 0u)) break;
          if (++guard > vlimit) { vlimit = 256; break; }  // anti-hang valve
        }
      }

      // stage to wave-private LDS region (DS ops in-order within a wave;
      // this wave's MFMA reads exactly the region it writes -> no barrier)
      *(v4u*)(rbuf64 + 0 * 1032 + tid * 2) = d0;
      *(v4u*)(rbuf64 + 1 * 1032 + tid * 2) = d1;
      *(v4u*)(rbuf64 + 2 * 1032 + tid * 2) = d2;
      *(v4u*)(rbuf64 + 3 * 1032 + tid * 2) = d3;
    }

    // ---- B-frags: lane holds r[b=n&3][k = wave*512+f*32+g*8+j]
    // 4 independent accumulator chains: dependent-latency -> issue-limited
    const unsigned short* rb = rbufs + (n & 3) * 4128 + wave * 512 + g * 8;
    v4f ac0 = {0.f, 0.f, 0.f, 0.f}, ac1 = {0.f, 0.f, 0.f, 0.f};
    v4f ac2 = {0.f, 0.f, 0.f, 0.f}, ac3 = {0.f, 0.f, 0.f, 0.f};
#pragma unroll
    for (int f = 0; f < 16; f += 4) {
      v8s b0 = *(const v8s*)(rb + (f + 0) * 32);
      v8s b1 = *(const v8s*)(rb + (f + 1) * 32);
      v8s b2 = *(const v8s*)(rb + (f + 2) * 32);
      v8s b3 = *(const v8s*)(rb + (f + 3) * 32);
      ac0 = __builtin_amdgcn_mfma_f32_16x16x32_bf16(wfrag[f + 0], b0, ac0, 0, 0, 0);
      ac1 = __builtin_amdgcn_mfma_f32_16x16x32_bf16(wfrag[f + 1], b1, ac1, 0, 0, 0);
      ac2 = __builtin_amdgcn_mfma_f32_16x16x32_bf16(wfrag[f + 2], b2, ac2, 0, 0, 0);
      ac3 = __builtin_amdgcn_mfma_f32_16x16x32_bf16(wfrag[f + 3], b3, ac3, 0, 0, 0);
    }
    red[slot][wave][lane] = (ac0 + ac1) + (ac2 + ac3);
    __syncthreads();  // reduction barrier (red double-buffered: only one/step)

    if (wave == 0) {
      // pairwise tree: 3-deep dependent chain instead of 7-deep
      v4f s01 = red[slot][0][lane] + red[slot][1][lane];
      v4f s23 = red[slot][2][lane] + red[slot][3][lane];
      v4f s45 = red[slot][4][lane] + red[slot][5][lane];
      v4f s67 = red[slot][6][lane] + red[slot][7][lane];
      v4f s = (s01 + s23) + (s45 + s67);
      const int ph = t / 500;  // 0 fix, 1 sample, 2 delay, 3 test, 4 response
#pragma unroll
      for (int q = 0; q < 4; ++q) {
        float e = (ph == 1) ? esmp[q] : ((ph == 3) ? etst[q] : 0.f);
        float pre = s[q] + bias[q] + e;
        float rl = pre > 0.f ? pre : 0.f;
        float nq = (q == 0) ? nz.x : (q == 1) ? nz.y : (q == 2) ? nz.z : nz.w;
        rst[q] = 0.8f * rst[q] + 0.2f * rl + 0.02f * nq;
      }
      if (n < 4) {  // publish FIRST (before bookkeeping): every cycle earlier
                    // here is a cycle off every consumer's discovery chain.
        u64 v = (u64)pack_bf2(rst[0], rst[1]) |
                ((u64)pack_bf2(rst[2], rst[3]) << 32);
        v = (v & ~1ull) | (u64)(((t + 1) >> 1) & 1u);
        u64* dst =
            (u64*)(ring + ((size_t)((t + 1) & 1) * 4 + n) * NC + row0 + g * 4);
        asm volatile("global_atomic_swap_x2 %0, %1, off sc1"
                     :: "v"(dst), "v"(v) : "memory");
      }
      if (t >= 1000 && t < 1500) {
#pragma unroll
        for (int q = 0; q < 4; ++q) tmem[q] += rst[q];
      }
      if (t >= 2000) {
#pragma unroll
        for (int q = 0; q < 4; ++q) tout[q] += rst[q];
      }
      // no ack, no tag: validity travels inside the data
    }
  }

  // ---- readout partials: out[s][b][o] += sum_i w[o][i] * tsum[b][i]
  if (wave == 0) {
    float pm0 = 0, pm1 = 0, po0 = 0, po1 = 0;
#pragma unroll
    for (int q = 0; q < 4; ++q) {
      int i = row0 + g * 4 + q;
      pm0 += mem_w[i] * tmem[q];
      pm1 += mem_w[NC + i] * tmem[q];
      po0 += out_w[i] * tout[q];
      po1 += out_w[NC + i] * tout[q];
    }
    pm0 += __shfl_xor(pm0, 16); pm0 += __shfl_xor(pm0, 32);
    pm1 += __shfl_xor(pm1, 16); pm1 += __shfl_xor(pm1, 32);
    po0 += __shfl_xor(po0, 16); po0 += __shfl_xor(po0, 32);
    po1 += __shfl_xor(po1, 16); po1 += __shfl_xor(po1, 32);
    if (lane < 4) {
      atomicAdd(&accum[lane * 2 + 0], pm0);
      atomicAdd(&accum[lane * 2 + 1], pm1);
      atomicAdd(&accum[8 + lane * 2 + 0], po0);
      atomicAdd(&accum[8 + lane * 2 + 1], po1);
    }
  }
}

// Output is FLOAT32 (reference returns f32)
__global__ void rnn_final(const float* __restrict__ ws, float* __restrict__ out) {
  int i = threadIdx.x;
  if (i < 16) out[i] = ws[256 + i] * (1.0f / 500.0f);
}

extern "C" void kernel_launch(void* const* d_in, const int* in_sizes, int n_in,
                              void* d_out, int out_size, void* d_ws, size_t ws_size,
                              hipStream_t stream) {
  (void)in_sizes; (void)n_in; (void)out_size; (void)ws_size;
  const float* x     = (const float*)d_in[0];
  const float* rec_w = (const float*)d_in[1];
  const float* rec_b = (const float*)d_in[2];
  const float* inp_w = (const float*)d_in[3];
  const float* out_w = (const float*)d_in[4];
  const float* mem_w = (const float*)d_in[5];
  const float* noise = (const float*)d_in[6];
  float* ws = (float*)d_ws;

  rnn_init<<<(WS_WORDS + 255) / 256, 256, 0, stream>>>((unsigned*)d_ws);
  rnn_persist<<<256, 512, 0, stream>>>(x, rec_w, rec_b, inp_w, out_w, mem_w,
                                       noise, ws);
  rnn_final<<<1, 64, 0, stream>>>(ws, (float*)d_out);
}